// Round 4
// baseline (604.229 us; speedup 1.0000x reference)
//
#include <hip/hip_runtime.h>
#include <hip/hip_bf16.h>

// Swin block fp32 I/O, MFMA bf16 compute. B=8,H=W=128,C=192,NH=6,hd=32,WS=8,SS=4.
// Round 9: MLP split. Fused k_mlp was structurally LDS/staging-bound (every
// 128-row block re-staged all 602 KB of w1+w2 because oacc regs cap the row
// tile). Split: k_mlp1 (LN + MLP1 + GELU, w1 half LDS-resident, staged once)
// and k_mlp2 (MLP2 + residual, w2 in 4 resident 76.8 KB k-chunks), pipelined
// over 4 row-chunks of 32768 rows with h (bf16 [32768][768]) reusing the Og
// region (exactly 50.33 MB). Grid 256 = 1 block/CU everywhere.
// k_attn / k_proj unchanged. k_prep: w2 image now [4][192][200] k-chunk-major.
//
// MFMA 16x16x32 bf16 layouts (HW-verified):
//   A: a[j] = A[m=lane&15][k=quad*8+j]
//   B: b[j] = B[k=quad*8+j][n=lane&15]
//   D: d[reg] = D[row=quad*4+reg][col=lane&15]

typedef __hip_bfloat16 bf16;
typedef __attribute__((ext_vector_type(8))) short bfrag;
typedef __attribute__((ext_vector_type(4))) float ffrag;

union bfu { bf16 h[8]; bfrag v; };

__device__ __forceinline__ float b2f(bf16 v) { return __bfloat162float(v); }
__device__ __forceinline__ bf16  f2b(float v) { return __float2bfloat16(v); }

#define MFMA(a, b, c) __builtin_amdgcn_mfma_f32_16x16x32_bf16((a), (b), (c), 0, 0, 0)

// workspace byte offsets
#define WS_XRES  0ULL
#define WS_OG    100663296ULL                  // bf16 [131072][192] attn out; reused as h [32768][768]
#define WS_QKVTG 150994944ULL                  // bf16 [2][320][200] group-contiguous qkv_w^T
#define WS_QBG   151250944ULL                  // f32  [2][320] group-contiguous qkv_b
#define WS_PROJT 151253504ULL                  // bf16 [192][200]
#define WS_W1T   151330304ULL                  // bf16 [768][200]
#define WS_W2T   151637504ULL                  // bf16 [4][192][200] k-chunk-major w2
#define WS_SB    152006144ULL                  // bf16 [4][6][64][64]

// async contiguous global->LDS copy; 256 threads (4-wave stride)
__device__ __forceinline__ void stage_lds(const void* g, void* l, int nbytes, int t) {
    const int lane16 = (t & 63) * 16;
    for (int base = (t >> 6) * 1024; base < nbytes; base += 4096) {
        if (base + lane16 < nbytes) {
            __builtin_amdgcn_global_load_lds(
                (const __attribute__((address_space(1))) void*)((const char*)g + base + lane16),
                (__attribute__((address_space(3))) void*)((char*)l + base),
                16, 0, 0);
        }
    }
}

// async contiguous global->LDS copy; 512 threads (8-wave stride)
__device__ __forceinline__ void stage_lds8(const void* g, void* l, int nbytes, int t) {
    const int lane16 = (t & 63) * 16;
    for (int base = (t >> 6) * 1024; base < nbytes; base += 8192) {
        if (base + lane16 < nbytes) {
            __builtin_amdgcn_global_load_lds(
                (const __attribute__((address_space(1))) void*)((const char*)g + base + lane16),
                (__attribute__((address_space(3))) void*)((char*)l + base),
                16, 0, 0);
        }
    }
}

__device__ __forceinline__ float gelu_t(float x) {
    float y = x * (1.5957691216057308f + 0.07135481627f * x * x);
    return x * (1.f / (1.f + __expf(-y)));
}

// ---------------------------------------------------------------------------
// k_prep: 2237 x 256 covers 572544 elements
// ---------------------------------------------------------------------------
__global__ __launch_bounds__(256) void k_prep(
    const float* __restrict__ qkv_w, const float* __restrict__ qkv_b,
    const float* __restrict__ proj_w, const float* __restrict__ w1,
    const float* __restrict__ w2, const float* __restrict__ rpb,
    char* __restrict__ ws)
{
    int i = blockIdx.x * 256 + threadIdx.x;
    bf16*  qkvTg = (bf16*)(ws + WS_QKVTG);
    float* qbg   = (float*)(ws + WS_QBG);
    bf16*  projT = (bf16*)(ws + WS_PROJT);
    bf16*  w1T   = (bf16*)(ws + WS_W1T);
    bf16*  w2T   = (bf16*)(ws + WS_W2T);
    bf16*  sbB   = (bf16*)(ws + WS_SB);

    if (i < 128000) {                          // qkvTg [2][320][200]
        int g = i / 64000, rem = i % 64000;
        int c = rem / 200, k = rem % 200;
        float v = 0.f;
        if (k < 192) {
            if (c < 96)       v = qkv_w[k * 576 + g * 96 + c];
            else if (c < 192) v = qkv_w[k * 576 + 192 + g * 96 + (c - 96)];
            else if (c < 288) v = qkv_w[k * 576 + 384 + g * 96 + (c - 192)];
        }
        qkvTg[i] = f2b(v);
    } else if (i < 128640) {                   // qbg [2][320]
        int j = i - 128000;
        int g = j / 320, c = j % 320;
        float v = 0.f;
        if (c < 96)       v = qkv_b[g * 96 + c];
        else if (c < 192) v = qkv_b[192 + g * 96 + (c - 96)];
        else if (c < 288) v = qkv_b[384 + g * 96 + (c - 192)];
        qbg[j] = v;
    } else if (i < 167040) {                   // projT [192][200]
        int j = i - 128640;
        int c = j / 200, k = j % 200;
        projT[j] = f2b(k < 192 ? proj_w[k * 192 + c] : 0.f);
    } else if (i < 320640) {                   // w1T [768][200]
        int j = i - 167040;
        int c = j / 200, k = j % 200;
        w1T[j] = f2b(k < 192 ? w1[k * 768 + c] : 0.f);
    } else if (i < 474240) {                   // w2T [4][192][200] (kc-major)
        int j = i - 320640;
        int kc = j / 38400, r = (j % 38400) / 200, kk = j % 200;
        w2T[j] = f2b(kk < 192 ? w2[(kc * 192 + kk) * 192 + r] : 0.f);
    } else if (i < 572544) {                   // sbB [4][6][64][64]
        int j = i - 474240;
        int cls = j / 24576, h = (j % 24576) / 4096;
        int ii = (j % 4096) / 64, jj = j % 64;
        int ri = ii >> 3, ci = ii & 7, rj = jj >> 3, cj = jj & 7;
        float bias = rpb[(((ri - rj + 7) * 15) + (ci - cj + 7)) * 6 + h];
        int clsR = cls >> 1, clsC = cls & 1;
        int regi = (clsR ? (ri < 4 ? 1 : 2) : 0) * 3 + (clsC ? (ci < 4 ? 1 : 2) : 0);
        int regj = (clsR ? (rj < 4 ? 1 : 2) : 0) * 3 + (clsC ? (cj < 4 ? 1 : 2) : 0);
        sbB[j] = f2b(bias + (regi == regj ? 0.f : -100.f));
    }
}

// ---------------------------------------------------------------------------
// k_attn: one window/block, 4 waves x 16 rows. qkv weights: 9x32-col chunks,
// double-buffered, prefetched one chunk ahead. LDS 77824 -> 2 blocks/CU.
// ---------------------------------------------------------------------------
__global__ __launch_bounds__(256, 2) void k_attn(
    const float* __restrict__ x, const char* __restrict__ ws,
    bf16* __restrict__ Og)
{
    __shared__ __align__(16) unsigned char smem[77824];
    bf16*  sWb = (bf16*)(smem);            // 2 x [32][200] double-buffered chunk
    bf16*  sQ  = (bf16*)(smem + 25600);    // [64][104]
    bf16*  sK  = (bf16*)(smem + 38912);    // [64][104]
    bf16*  sVT = (bf16*)(smem + 52224);    // [96][72]
    bf16*  sP  = (bf16*)(smem + 66048);    // [4][16][72]
    float* sQB = (float*)(smem + 75264);   // [640] qkv bias (both groups)

    const bf16*  qkvTg = (const bf16*)(ws + WS_QKVTG);
    const float* qbg   = (const float*)(ws + WS_QBG);
    const bf16*  sbB   = (const bf16*)(ws + WS_SB);

    const int t    = threadIdx.x;
    const int lane = t & 63, quad = lane >> 4, l15 = lane & 15;
    const int wave = t >> 6, r0 = wave * 16;
    const int win = blockIdx.x;
    const int b   = win >> 8;
    const int wi  = win & 255;
    const int wh  = wi >> 4, wwi = wi & 15;

    // prologue staging: biases + first chunk (hidden under aX gather/convert)
    stage_lds(qbg, smem + 75264, 2560, t);
    stage_lds(qkvTg, sWb, 12800, t);

    // A-frags of gathered x window, direct from global (fp32 -> bf16)
    bfrag aX[6];
    {
        int row = r0 + l15;
        int rr = row >> 3, cc = row & 7;
        int hs  = (wh * 8 + rr + 4) & 127;
        int wsx = (wwi * 8 + cc + 4) & 127;
        const float* xrow = x + ((size_t)(b * 16384 + hs * 128 + wsx)) * 192;
        #pragma unroll
        for (int kb = 0; kb < 6; kb++) {
            float4 f0 = *(const float4*)(xrow + kb * 32 + quad * 8);
            float4 f1 = *(const float4*)(xrow + kb * 32 + quad * 8 + 4);
            bfu u;
            u.h[0] = f2b(f0.x); u.h[1] = f2b(f0.y); u.h[2] = f2b(f0.z); u.h[3] = f2b(f0.w);
            u.h[4] = f2b(f1.x); u.h[5] = f2b(f1.y); u.h[6] = f2b(f1.z); u.h[7] = f2b(f1.w);
            aX[kb] = u.v;
        }
    }

    const int cls = ((wh == 15) ? 2 : 0) + ((wwi == 15) ? 1 : 0);
    const bf16* bBc = sbB + (size_t)cls * 24576;
    bf16* sPw = sP + wave * 16 * 72;

    __syncthreads();                           // chunk0 + biases staged

    int pb = 0;
    for (int g = 0; g < 2; g++) {
        // ---- qkv for head group g: 9 chunks of 32 cols, 2-phase pipeline ----
        for (int c = 0; c < 9; c++) {
            if (c < 8)
                stage_lds(qkvTg + (size_t)(g * 320 + (c + 1) * 32) * 200,
                          sWb + (pb ^ 1) * 6400, 12800, t);
            else if (g == 0)
                stage_lds(qkvTg + (size_t)320 * 200,
                          sWb + (pb ^ 1) * 6400, 12800, t);
            const bf16* sW = sWb + pb * 6400;
            #pragma unroll
            for (int ct = 0; ct < 2; ct++) {
                int c0 = c * 32 + ct * 16;
                bfrag bw[6];
                #pragma unroll
                for (int kb = 0; kb < 6; kb++)
                    bw[kb] = *(const bfrag*)&sW[(ct * 16 + l15) * 200 + kb * 32 + quad * 8];
                ffrag acc = {0.f, 0.f, 0.f, 0.f};
                #pragma unroll
                for (int kb = 0; kb < 6; kb++) acc = MFMA(aX[kb], bw[kb], acc);
                float bias = sQB[g * 320 + c0 + l15];
                #pragma unroll
                for (int reg = 0; reg < 4; reg++) {
                    int r = r0 + quad * 4 + reg;
                    float v = acc[reg] + bias;
                    if (c0 < 96)       sQ[r * 104 + c0 + l15] = f2b(v);
                    else if (c0 < 192) sK[r * 104 + (c0 - 96) + l15] = f2b(v);
                    else               sVT[(c0 - 192 + l15) * 72 + r] = f2b(v);
                }
            }
            __syncthreads();                   // drains prefetch; chunk c+1 ready
            pb ^= 1;
        }
        // ---- attention heads g*3 .. g*3+2 (no staging in flight here) ----
        for (int hl = 0; hl < 3; hl++) {
            int h = g * 3 + hl;
            bfrag aQ = *(const bfrag*)&sQ[(r0 + l15) * 104 + hl * 32 + quad * 8];
            ffrag Sf[4];
            #pragma unroll
            for (int jt = 0; jt < 4; jt++) {
                bfrag bK = *(const bfrag*)&sK[(jt * 16 + l15) * 104 + hl * 32 + quad * 8];
                ffrag z = {0.f, 0.f, 0.f, 0.f};
                Sf[jt] = MFMA(aQ, bK, z);
            }
            const bf16* bb = bBc + h * 4096 + (r0 + quad * 4) * 64 + l15;
            #pragma unroll
            for (int jt = 0; jt < 4; jt++)
                #pragma unroll
                for (int reg = 0; reg < 4; reg++)
                    Sf[jt][reg] = Sf[jt][reg] * 0.1767766952966369f
                                + b2f(bb[reg * 64 + jt * 16]);
            #pragma unroll
            for (int reg = 0; reg < 4; reg++) {
                float m = fmaxf(fmaxf(Sf[0][reg], Sf[1][reg]), fmaxf(Sf[2][reg], Sf[3][reg]));
                m = fmaxf(m, __shfl_xor(m, 1)); m = fmaxf(m, __shfl_xor(m, 2));
                m = fmaxf(m, __shfl_xor(m, 4)); m = fmaxf(m, __shfl_xor(m, 8));
                float s = 0.f;
                #pragma unroll
                for (int jt = 0; jt < 4; jt++) { Sf[jt][reg] = __expf(Sf[jt][reg] - m); s += Sf[jt][reg]; }
                s += __shfl_xor(s, 1); s += __shfl_xor(s, 2);
                s += __shfl_xor(s, 4); s += __shfl_xor(s, 8);
                float inv = 1.f / s;
                int prow = (quad * 4 + reg) * 72;
                #pragma unroll
                for (int jt = 0; jt < 4; jt++)
                    sPw[prow + jt * 16 + l15] = f2b(Sf[jt][reg] * inv);
            }
            bfrag aP0 = *(const bfrag*)&sPw[l15 * 72 + quad * 8];
            bfrag aP1 = *(const bfrag*)&sPw[l15 * 72 + 32 + quad * 8];
            #pragma unroll
            for (int ct = 0; ct < 2; ct++) {
                bfrag bV0 = *(const bfrag*)&sVT[(hl * 32 + ct * 16 + l15) * 72 + quad * 8];
                bfrag bV1 = *(const bfrag*)&sVT[(hl * 32 + ct * 16 + l15) * 72 + 32 + quad * 8];
                ffrag z = {0.f, 0.f, 0.f, 0.f};
                ffrag o = MFMA(aP1, bV1, MFMA(aP0, bV0, z));
                #pragma unroll
                for (int reg = 0; reg < 4; reg++)
                    Og[((size_t)win * 64 + r0 + quad * 4 + reg) * 192 + h * 32 + ct * 16 + l15]
                        = f2b(o[reg]);
            }
        }
        __syncthreads();                       // attn reads done before g1 writes
    }
}

// ---------------------------------------------------------------------------
// k_proj: 128 rows (2 windows)/block, 4 waves x 32 rows (rt=2).
// projT staged ONCE (76800 B), 1 barrier. -> xres (reverse-shift + residual)
// ---------------------------------------------------------------------------
__global__ __launch_bounds__(256, 2) void k_proj(
    const float* __restrict__ x, const float* __restrict__ proj_b,
    const char* __restrict__ ws, float* __restrict__ xres)
{
    __shared__ __align__(16) bf16 sWp[192 * 200];   // 76800 B

    const bf16* projT = (const bf16*)(ws + WS_PROJT);
    const bf16* Og    = (const bf16*)(ws + WS_OG);

    const int t    = threadIdx.x;
    const int lane = t & 63, quad = lane >> 4, l15 = lane & 15;
    const int wave = t >> 6, r0 = wave * 32;
    const size_t row0 = (size_t)blockIdx.x * 128;

    stage_lds(projT, sWp, 76800, t);

    // A-frags of O (global, bf16, contiguous 16B)
    bfrag aO[2][6];
    #pragma unroll
    for (int rt = 0; rt < 2; rt++)
        #pragma unroll
        for (int kb = 0; kb < 6; kb++)
            aO[rt][kb] = *(const bfrag*)&Og[(row0 + r0 + rt * 16 + l15) * 192 + kb * 32 + quad * 8];

    // token scatter addresses (reverse shift)
    size_t tokb[2][4];
    #pragma unroll
    for (int rt = 0; rt < 2; rt++)
        #pragma unroll
        for (int reg = 0; reg < 4; reg++) {
            int n = r0 + rt * 16 + quad * 4 + reg;
            int w2 = (int)(blockIdx.x * 2) + (n >> 6);
            int nl = n & 63;
            int b = w2 >> 8, wi = w2 & 255;
            int wh = wi >> 4, wwi = wi & 15;
            int sr = wh * 8 + (nl >> 3), sc = wwi * 8 + (nl & 7);
            int h2 = (sr + 4) & 127, w2c = (sc + 4) & 127;
            tokb[rt][reg] = ((size_t)(b * 16384 + h2 * 128 + w2c)) * 192;
        }

    __syncthreads();

    ffrag acc[2][12];
    #pragma unroll
    for (int rt = 0; rt < 2; rt++)
        #pragma unroll
        for (int ct = 0; ct < 12; ct++)
            acc[rt][ct] = (ffrag){0.f, 0.f, 0.f, 0.f};

    #pragma unroll
    for (int ct = 0; ct < 12; ct++) {
        bfrag bw[6];
        #pragma unroll
        for (int kb = 0; kb < 6; kb++)
            bw[kb] = *(const bfrag*)&sWp[(ct * 16 + l15) * 200 + kb * 32 + quad * 8];
        #pragma unroll
        for (int rt = 0; rt < 2; rt++)
            #pragma unroll
            for (int kb = 0; kb < 6; kb++)
                acc[rt][ct] = MFMA(aO[rt][kb], bw[kb], acc[rt][ct]);
    }

    #pragma unroll
    for (int rt = 0; rt < 2; rt++)
        #pragma unroll
        for (int ct = 0; ct < 12; ct++) {
            int col = ct * 16 + l15;
            float pb = proj_b[col];
            #pragma unroll
            for (int reg = 0; reg < 4; reg++) {
                size_t gi = tokb[rt][reg] + col;
                xres[gi] = acc[rt][ct][reg] + pb + x[gi];
            }
        }
}

// ---------------------------------------------------------------------------
// k_mlp1: LN + h = gelu(xn @ w1half + b1) for 32768 rows, hidden half per
// block. grid 256 = 128 row-blocks x 2 hid-halves; 512 thr = 8 waves x 32
// rows (rt=2). w1 half [384][200] = 153600 B LDS, staged ONCE. h -> hbuf.
// ---------------------------------------------------------------------------
__global__ __launch_bounds__(512, 2) void k_mlp1(
    const float* __restrict__ xres, const float* __restrict__ g,
    const float* __restrict__ bb, const float* __restrict__ b1,
    const char* __restrict__ ws, bf16* __restrict__ hbuf, int row0c)
{
    __shared__ __align__(16) bf16 sW1[384 * 200];   // 153600 B

    const bf16* w1T = (const bf16*)(ws + WS_W1T);

    const int t    = threadIdx.x;
    const int lane = t & 63, quad = lane >> 4, l15 = lane & 15;
    const int wave = t >> 6, r0 = wave * 32;
    const int ht = blockIdx.x >> 7, rb = blockIdx.x & 127;
    const size_t rowb = (size_t)row0c + (size_t)rb * 256;

    stage_lds8(w1T + (size_t)ht * 384 * 200, sW1, 153600, t);

    // LN stats + A-frag build, 2 row-tiles (rows r0+rt*16+l15)
    bfrag aX[2][6];
    #pragma unroll
    for (int rt = 0; rt < 2; rt++) {
        const float* xrow = xres + (rowb + r0 + rt * 16 + l15) * 192;
        float s = 0.f, sq = 0.f;
        #pragma unroll
        for (int kb = 0; kb < 6; kb++) {
            float4 f0 = *(const float4*)(xrow + kb * 32 + quad * 8);
            float4 f1 = *(const float4*)(xrow + kb * 32 + quad * 8 + 4);
            s  += f0.x + f0.y + f0.z + f0.w + f1.x + f1.y + f1.z + f1.w;
            sq += f0.x*f0.x + f0.y*f0.y + f0.z*f0.z + f0.w*f0.w
                + f1.x*f1.x + f1.y*f1.y + f1.z*f1.z + f1.w*f1.w;
        }
        s  += __shfl_xor(s, 16);  s  += __shfl_xor(s, 32);
        sq += __shfl_xor(sq, 16); sq += __shfl_xor(sq, 32);
        float mean = s * (1.f / 192.f);
        float var  = sq * (1.f / 192.f) - mean * mean;
        float rstd = rsqrtf(var + 1e-5f);
        #pragma unroll
        for (int kb = 0; kb < 6; kb++) {
            int c = kb * 32 + quad * 8;
            float4 f0 = *(const float4*)(xrow + c);
            float4 f1 = *(const float4*)(xrow + c + 4);
            float4 g0 = *(const float4*)(g + c);
            float4 g1 = *(const float4*)(g + c + 4);
            float4 c0 = *(const float4*)(bb + c);
            float4 c1 = *(const float4*)(bb + c + 4);
            bfu u;
            u.h[0] = f2b((f0.x - mean) * rstd * g0.x + c0.x);
            u.h[1] = f2b((f0.y - mean) * rstd * g0.y + c0.y);
            u.h[2] = f2b((f0.z - mean) * rstd * g0.z + c0.z);
            u.h[3] = f2b((f0.w - mean) * rstd * g0.w + c0.w);
            u.h[4] = f2b((f1.x - mean) * rstd * g1.x + c1.x);
            u.h[5] = f2b((f1.y - mean) * rstd * g1.y + c1.y);
            u.h[6] = f2b((f1.z - mean) * rstd * g1.z + c1.z);
            u.h[7] = f2b((f1.w - mean) * rstd * g1.w + c1.w);
            aX[rt][kb] = u.v;
        }
    }

    __syncthreads();                 // w1 half staged (drains vmcnt)

    for (int ct = 0; ct < 24; ct++) {
        bfrag bw[6];
        #pragma unroll
        for (int kb = 0; kb < 6; kb++)
            bw[kb] = *(const bfrag*)&sW1[(ct * 16 + l15) * 200 + kb * 32 + quad * 8];
        float bias = b1[ht * 384 + ct * 16 + l15];
        #pragma unroll
        for (int rt = 0; rt < 2; rt++) {
            ffrag a = {0.f, 0.f, 0.f, 0.f};
            #pragma unroll
            for (int kb = 0; kb < 6; kb++) a = MFMA(aX[rt][kb], bw[kb], a);
            #pragma unroll
            for (int reg = 0; reg < 4; reg++) {
                size_t hr = (size_t)rb * 256 + r0 + rt * 16 + quad * 4 + reg;
                hbuf[hr * 768 + ht * 384 + ct * 16 + l15] =
                    f2b(gelu_t(a[reg] + bias));
            }
        }
    }
}

// ---------------------------------------------------------------------------
// k_mlp2: out = h @ w2 + xres + b2 for 32768 rows. grid 256, 512 thr =
// 8 waves x 16 rows. w2 in 4 k-chunks [192][200] = 76800 B, double-buffered
// (LDS 153600), prefetched one chunk ahead; acc[12] persistent (48 regs).
// ---------------------------------------------------------------------------
__global__ __launch_bounds__(512, 2) void k_mlp2(
    const bf16* __restrict__ hbuf, const float* __restrict__ xres,
    const float* __restrict__ b2, const char* __restrict__ ws,
    float* __restrict__ out, int row0c)
{
    __shared__ __align__(16) bf16 sW2[2][192 * 200];   // 2 x 76800 B

    const bf16* w2T = (const bf16*)(ws + WS_W2T);

    const int t    = threadIdx.x;
    const int lane = t & 63, quad = lane >> 4, l15 = lane & 15;
    const int wave = t >> 6, r0 = wave * 16;
    const size_t rowbl = (size_t)blockIdx.x * 128;     // chunk-local rows

    stage_lds8(w2T, sW2[0], 76800, t);

    ffrag acc[12];
    #pragma unroll
    for (int ct = 0; ct < 12; ct++)
        acc[ct] = (ffrag){0.f, 0.f, 0.f, 0.f};

    __syncthreads();                 // chunk 0 staged (drains vmcnt)

    for (int kc = 0; kc < 4; kc++) {
        if (kc < 3)
            stage_lds8(w2T + (size_t)(kc + 1) * 38400, sW2[(kc + 1) & 1], 76800, t);
        const bf16* w2c = sW2[kc & 1];

        bfrag aH[6];
        #pragma unroll
        for (int kb = 0; kb < 6; kb++)
            aH[kb] = *(const bfrag*)&hbuf[(rowbl + r0 + l15) * 768
                                          + kc * 192 + kb * 32 + quad * 8];
        #pragma unroll
        for (int ct = 0; ct < 12; ct++) {
            bfrag bw[6];
            #pragma unroll
            for (int kb = 0; kb < 6; kb++)
                bw[kb] = *(const bfrag*)&w2c[(ct * 16 + l15) * 200 + kb * 32 + quad * 8];
            #pragma unroll
            for (int kb = 0; kb < 6; kb++)
                acc[ct] = MFMA(aH[kb], bw[kb], acc[ct]);
        }
        __syncthreads();             // drains prefetch; WAR-safe buffer swap
    }

    // epilogue: out = xres + mlp + b2
    const size_t rowg = (size_t)row0c + rowbl;
    #pragma unroll
    for (int ct = 0; ct < 12; ct++) {
        int col = ct * 16 + l15;
        float b2v = b2[col];
        #pragma unroll
        for (int reg = 0; reg < 4; reg++) {
            size_t gi = (rowg + r0 + quad * 4 + reg) * 192 + col;
            out[gi] = xres[gi] + acc[ct][reg] + b2v;
        }
    }
}

// ---------------------------------------------------------------------------
extern "C" void kernel_launch(void* const* d_in, const int* in_sizes, int n_in,
                              void* d_out, int out_size, void* d_ws, size_t ws_size,
                              hipStream_t stream)
{
    (void)in_sizes; (void)n_in; (void)out_size; (void)ws_size;

    const float* x      = (const float*)d_in[0];
    const float* qkv_w  = (const float*)d_in[1];
    const float* qkv_b  = (const float*)d_in[2];
    const float* proj_w = (const float*)d_in[3];
    const float* proj_b = (const float*)d_in[4];
    const float* rpb    = (const float*)d_in[5];
    const float* n2g    = (const float*)d_in[6];
    const float* n2b    = (const float*)d_in[7];
    const float* w1     = (const float*)d_in[8];
    const float* b1     = (const float*)d_in[9];
    const float* w2     = (const float*)d_in[10];
    const float* b2     = (const float*)d_in[11];

    char*  ws   = (char*)d_ws;
    float* xres = (float*)(ws + WS_XRES);
    bf16*  Og   = (bf16*)(ws + WS_OG);
    float* out  = (float*)d_out;

    hipLaunchKernelGGL(k_prep, dim3(2237), dim3(256), 0, stream,
                       qkv_w, qkv_b, proj_w, w1, w2, rpb, ws);
    hipLaunchKernelGGL(k_attn, dim3(2048), dim3(256), 0, stream,
                       x, ws, Og);
    hipLaunchKernelGGL(k_proj, dim3(1024), dim3(256), 0, stream,
                       x, proj_b, ws, xres);
    for (int c = 0; c < 4; c++) {
        hipLaunchKernelGGL(k_mlp1, dim3(256), dim3(512), 0, stream,
                           xres, n2g, n2b, b1, ws, Og, c * 32768);
        hipLaunchKernelGGL(k_mlp2, dim3(256), dim3(512), 0, stream,
                           Og, xres, b2, ws, out, c * 32768);
    }
}

// Round 5
// 478.971 us; speedup vs baseline: 1.2615x; 1.2615x over previous
//
#include <hip/hip_runtime.h>
#include <hip/hip_bf16.h>

// Swin block fp32 I/O, MFMA bf16 compute. B=8,H=W=128,C=192,NH=6,hd=32,WS=8,SS=4.
// Round 10: revert k_mlp to R0 fused (168us known; R9 split cost ~300us).
// k_attn rewritten HEAD-MAJOR: qkv weight image reordered so each head's
// [Q32|K32|V32] cols are contiguous; 18 chunks of 32 cols (double-buffered),
// attention for head h runs right after its 3 chunks from small recycled
// buffers. LDS 51 KB -> 3 blocks/CU (12 waves/CU, was 8) for stall coverage.
//
// MFMA 16x16x32 bf16 layouts (HW-verified):
//   A: a[j] = A[m=lane&15][k=quad*8+j]
//   B: b[j] = B[k=quad*8+j][n=lane&15]
//   D: d[reg] = D[row=quad*4+reg][col=lane&15]

typedef __hip_bfloat16 bf16;
typedef __attribute__((ext_vector_type(8))) short bfrag;
typedef __attribute__((ext_vector_type(4))) float ffrag;

union bfu { bf16 h[8]; bfrag v; };

__device__ __forceinline__ float b2f(bf16 v) { return __bfloat162float(v); }
__device__ __forceinline__ bf16  f2b(float v) { return __float2bfloat16(v); }

#define MFMA(a, b, c) __builtin_amdgcn_mfma_f32_16x16x32_bf16((a), (b), (c), 0, 0, 0)

// workspace byte offsets
#define WS_XRES  0ULL
#define WS_OG    100663296ULL                  // bf16 [131072][192] attention output
#define WS_QKVTG 150994944ULL                  // bf16 [2][320][200] HEAD-MAJOR qkv_w^T
#define WS_QBG   151250944ULL                  // f32  [2][320] head-major qkv_b
#define WS_PROJT 151253504ULL                  // bf16 [192][200]
#define WS_W1T   151330304ULL                  // bf16 [768][200]
#define WS_W2T   151637504ULL                  // bf16 [12][192][72]
#define WS_SB    151969280ULL                  // bf16 [4][6][64][64]

// async contiguous global->LDS copy; 256 threads; handles partial tails
__device__ __forceinline__ void stage_lds(const void* g, void* l, int nbytes, int t) {
    const int lane16 = (t & 63) * 16;
    for (int base = (t >> 6) * 1024; base < nbytes; base += 4096) {
        if (base + lane16 < nbytes) {
            __builtin_amdgcn_global_load_lds(
                (const __attribute__((address_space(1))) void*)((const char*)g + base + lane16),
                (__attribute__((address_space(3))) void*)((char*)l + base),
                16, 0, 0);
        }
    }
}

__device__ __forceinline__ float gelu_t(float x) {
    float y = x * (1.5957691216057308f + 0.07135481627f * x * x);
    return x * (1.f / (1.f + __expf(-y)));
}

// ---------------------------------------------------------------------------
// k_prep: 2285 x 256 covers 584832 elements
// ---------------------------------------------------------------------------
__global__ __launch_bounds__(256) void k_prep(
    const float* __restrict__ qkv_w, const float* __restrict__ qkv_b,
    const float* __restrict__ proj_w, const float* __restrict__ w1,
    const float* __restrict__ w2, const float* __restrict__ rpb,
    char* __restrict__ ws)
{
    int i = blockIdx.x * 256 + threadIdx.x;
    bf16*  qkvTg = (bf16*)(ws + WS_QKVTG);
    float* qbg   = (float*)(ws + WS_QBG);
    bf16*  projT = (bf16*)(ws + WS_PROJT);
    bf16*  w1T   = (bf16*)(ws + WS_W1T);
    bf16*  w2T   = (bf16*)(ws + WS_W2T);
    bf16*  sbB   = (bf16*)(ws + WS_SB);

    if (i < 128000) {                          // qkvTg [2][320][200] head-major
        int g = i / 64000, rem = i % 64000;
        int c = rem / 200, k = rem % 200;
        float v = 0.f;
        if (k < 192 && c < 288) {
            int h = g * 3 + c / 96, j = c % 96;
            int src = (j < 32) ? (h * 32 + j)
                    : (j < 64) ? (192 + h * 32 + (j - 32))
                               : (384 + h * 32 + (j - 64));
            v = qkv_w[k * 576 + src];
        }
        qkvTg[i] = f2b(v);
    } else if (i < 128640) {                   // qbg [2][320] head-major
        int j = i - 128000;
        int g = j / 320, c = j % 320;
        float v = 0.f;
        if (c < 288) {
            int h = g * 3 + c / 96, jj = c % 96;
            int src = (jj < 32) ? (h * 32 + jj)
                    : (jj < 64) ? (192 + h * 32 + (jj - 32))
                                : (384 + h * 32 + (jj - 64));
            v = qkv_b[src];
        }
        qbg[j] = v;
    } else if (i < 167040) {                   // projT [192][200]
        int j = i - 128640;
        int c = j / 200, k = j % 200;
        projT[j] = f2b(k < 192 ? proj_w[k * 192 + c] : 0.f);
    } else if (i < 320640) {                   // w1T [768][200]
        int j = i - 167040;
        int c = j / 200, k = j % 200;
        w1T[j] = f2b(k < 192 ? w1[k * 768 + c] : 0.f);
    } else if (i < 486528) {                   // w2T [12][192][72]
        int j = i - 320640;
        int kc = j / 13824, r = (j % 13824) / 72, kk = j % 72;
        w2T[j] = f2b(kk < 64 ? w2[(kc * 64 + kk) * 192 + r] : 0.f);
    } else if (i < 584832) {                   // sbB [4][6][64][64]
        int j = i - 486528;
        int cls = j / 24576, h = (j % 24576) / 4096;
        int ii = (j % 4096) / 64, jj = j % 64;
        int ri = ii >> 3, ci = ii & 7, rj = jj >> 3, cj = jj & 7;
        float bias = rpb[(((ri - rj + 7) * 15) + (ci - cj + 7)) * 6 + h];
        int clsR = cls >> 1, clsC = cls & 1;
        int regi = (clsR ? (ri < 4 ? 1 : 2) : 0) * 3 + (clsC ? (ci < 4 ? 1 : 2) : 0);
        int regj = (clsR ? (rj < 4 ? 1 : 2) : 0) * 3 + (clsC ? (cj < 4 ? 1 : 2) : 0);
        sbB[j] = f2b(bias + (regi == regj ? 0.f : -100.f));
    }
}

// ---------------------------------------------------------------------------
// k_attn: one window/block, 4 waves x 16 rows, HEAD-MAJOR. 18 chunks of 32
// qkv cols (double-buffered, 2-phase); after each head's 3 chunks, its
// attention runs from recycled sQh/sKh/sVT. LDS 52224 -> 3 blocks/CU.
// ---------------------------------------------------------------------------
__global__ __launch_bounds__(256, 3) void k_attn(
    const float* __restrict__ x, const char* __restrict__ ws,
    bf16* __restrict__ Og)
{
    __shared__ __align__(16) unsigned char smem[52224];
    bf16*  sWb = (bf16*)(smem);            // 2 x [32][200] double-buffered chunk
    bf16*  sQh = (bf16*)(smem + 25600);    // [64][40] head Q
    bf16*  sKh = (bf16*)(smem + 30720);    // [64][40] head K
    bf16*  sVT = (bf16*)(smem + 35840);    // [32][72] head V^T
    bf16*  sP  = (bf16*)(smem + 40448);    // [4][16][72]
    float* sQB = (float*)(smem + 49664);   // [640] qkv bias (head-major)

    const bf16*  qkvTg = (const bf16*)(ws + WS_QKVTG);
    const float* qbg   = (const float*)(ws + WS_QBG);
    const bf16*  sbB   = (const bf16*)(ws + WS_SB);

    const int t    = threadIdx.x;
    const int lane = t & 63, quad = lane >> 4, l15 = lane & 15;
    const int wave = t >> 6, r0 = wave * 16;
    const int win = blockIdx.x;
    const int b   = win >> 8;
    const int wi  = win & 255;
    const int wh  = wi >> 4, wwi = wi & 15;

    // prologue staging: biases + chunk 0 (hidden under aX gather/convert)
    stage_lds(qbg, smem + 49664, 2560, t);
    stage_lds(qkvTg, sWb, 12800, t);

    // A-frags of gathered x window, direct from global (fp32 -> bf16)
    bfrag aX[6];
    {
        int row = r0 + l15;
        int rr = row >> 3, cc = row & 7;
        int hs  = (wh * 8 + rr + 4) & 127;
        int wsx = (wwi * 8 + cc + 4) & 127;
        const float* xrow = x + ((size_t)(b * 16384 + hs * 128 + wsx)) * 192;
        #pragma unroll
        for (int kb = 0; kb < 6; kb++) {
            float4 f0 = *(const float4*)(xrow + kb * 32 + quad * 8);
            float4 f1 = *(const float4*)(xrow + kb * 32 + quad * 8 + 4);
            bfu u;
            u.h[0] = f2b(f0.x); u.h[1] = f2b(f0.y); u.h[2] = f2b(f0.z); u.h[3] = f2b(f0.w);
            u.h[4] = f2b(f1.x); u.h[5] = f2b(f1.y); u.h[6] = f2b(f1.z); u.h[7] = f2b(f1.w);
            aX[kb] = u.v;
        }
    }

    const int cls = ((wh == 15) ? 2 : 0) + ((wwi == 15) ? 1 : 0);
    const bf16* bBc = sbB + (size_t)cls * 24576;
    bf16* sPw = sP + wave * 16 * 72;

    __syncthreads();                           // chunk0 + biases staged

    int pb = 0;
    int cb = 0;                                // col base in [2][320] image
    for (int cc = 0; cc < 18; cc++) {
        const int h = cc / 3, cpart = cc - h * 3;
        // stage next chunk (col base: +32, or jump 256->320 at group switch)
        if (cc < 17) {
            int cbn = (cc == 8) ? 320 : cb + 32;
            stage_lds(qkvTg + (size_t)cbn * 200, sWb + (pb ^ 1) * 6400, 12800, t);
        }
        const bf16* sW = sWb + pb * 6400;
        #pragma unroll
        for (int ct = 0; ct < 2; ct++) {
            bfrag bw[6];
            #pragma unroll
            for (int kb = 0; kb < 6; kb++)
                bw[kb] = *(const bfrag*)&sW[(ct * 16 + l15) * 200 + kb * 32 + quad * 8];
            ffrag acc = {0.f, 0.f, 0.f, 0.f};
            #pragma unroll
            for (int kb = 0; kb < 6; kb++) acc = MFMA(aX[kb], bw[kb], acc);
            float bias = sQB[cb + ct * 16 + l15];
            const int cl = ct * 16 + l15;
            #pragma unroll
            for (int reg = 0; reg < 4; reg++) {
                int r = r0 + quad * 4 + reg;
                float v = acc[reg] + bias;
                if (cpart == 0)      sQh[r * 40 + cl] = f2b(v);
                else if (cpart == 1) sKh[r * 40 + cl] = f2b(v);
                else                 sVT[cl * 72 + r] = f2b(v);
            }
        }
        __syncthreads();                       // drains prefetch; scatters visible
        pb ^= 1;
        cb = (cc == 8) ? 320 : cb + 32;

        if (cpart == 2) {
            // ---- attention head h (sQh/sKh/sVT complete) ----
            bfrag aQ = *(const bfrag*)&sQh[(r0 + l15) * 40 + quad * 8];
            ffrag Sf[4];
            #pragma unroll
            for (int jt = 0; jt < 4; jt++) {
                bfrag bK = *(const bfrag*)&sKh[(jt * 16 + l15) * 40 + quad * 8];
                ffrag z = {0.f, 0.f, 0.f, 0.f};
                Sf[jt] = MFMA(aQ, bK, z);
            }
            const bf16* bb = bBc + h * 4096 + (r0 + quad * 4) * 64 + l15;
            #pragma unroll
            for (int jt = 0; jt < 4; jt++)
                #pragma unroll
                for (int reg = 0; reg < 4; reg++)
                    Sf[jt][reg] = Sf[jt][reg] * 0.1767766952966369f
                                + b2f(bb[reg * 64 + jt * 16]);
            #pragma unroll
            for (int reg = 0; reg < 4; reg++) {
                float m = fmaxf(fmaxf(Sf[0][reg], Sf[1][reg]), fmaxf(Sf[2][reg], Sf[3][reg]));
                m = fmaxf(m, __shfl_xor(m, 1)); m = fmaxf(m, __shfl_xor(m, 2));
                m = fmaxf(m, __shfl_xor(m, 4)); m = fmaxf(m, __shfl_xor(m, 8));
                float s = 0.f;
                #pragma unroll
                for (int jt = 0; jt < 4; jt++) { Sf[jt][reg] = __expf(Sf[jt][reg] - m); s += Sf[jt][reg]; }
                s += __shfl_xor(s, 1); s += __shfl_xor(s, 2);
                s += __shfl_xor(s, 4); s += __shfl_xor(s, 8);
                float inv = 1.f / s;
                int prow = (quad * 4 + reg) * 72;
                #pragma unroll
                for (int jt = 0; jt < 4; jt++)
                    sPw[prow + jt * 16 + l15] = f2b(Sf[jt][reg] * inv);
            }
            bfrag aP0 = *(const bfrag*)&sPw[l15 * 72 + quad * 8];
            bfrag aP1 = *(const bfrag*)&sPw[l15 * 72 + 32 + quad * 8];
            #pragma unroll
            for (int ct = 0; ct < 2; ct++) {
                bfrag bV0 = *(const bfrag*)&sVT[(ct * 16 + l15) * 72 + quad * 8];
                bfrag bV1 = *(const bfrag*)&sVT[(ct * 16 + l15) * 72 + 32 + quad * 8];
                ffrag z = {0.f, 0.f, 0.f, 0.f};
                ffrag o = MFMA(aP1, bV1, MFMA(aP0, bV0, z));
                #pragma unroll
                for (int reg = 0; reg < 4; reg++)
                    Og[((size_t)win * 64 + r0 + quad * 4 + reg) * 192 + h * 32 + ct * 16 + l15]
                        = f2b(o[reg]);
            }
            if (cc < 17) __syncthreads();      // attn reads done before next head
        }
    }
}

// ---------------------------------------------------------------------------
// k_proj: 128 rows (2 windows)/block, 4 waves x 32 rows (rt=2).
// projT staged ONCE (76800 B), 1 barrier. -> xres (reverse-shift + residual)
// ---------------------------------------------------------------------------
__global__ __launch_bounds__(256, 2) void k_proj(
    const float* __restrict__ x, const float* __restrict__ proj_b,
    const char* __restrict__ ws, float* __restrict__ xres)
{
    __shared__ __align__(16) bf16 sWp[192 * 200];   // 76800 B

    const bf16* projT = (const bf16*)(ws + WS_PROJT);
    const bf16* Og    = (const bf16*)(ws + WS_OG);

    const int t    = threadIdx.x;
    const int lane = t & 63, quad = lane >> 4, l15 = lane & 15;
    const int wave = t >> 6, r0 = wave * 32;
    const size_t row0 = (size_t)blockIdx.x * 128;

    stage_lds(projT, sWp, 76800, t);

    // A-frags of O (global, bf16, contiguous 16B)
    bfrag aO[2][6];
    #pragma unroll
    for (int rt = 0; rt < 2; rt++)
        #pragma unroll
        for (int kb = 0; kb < 6; kb++)
            aO[rt][kb] = *(const bfrag*)&Og[(row0 + r0 + rt * 16 + l15) * 192 + kb * 32 + quad * 8];

    // token scatter addresses (reverse shift)
    size_t tokb[2][4];
    #pragma unroll
    for (int rt = 0; rt < 2; rt++)
        #pragma unroll
        for (int reg = 0; reg < 4; reg++) {
            int n = r0 + rt * 16 + quad * 4 + reg;
            int w2 = (int)(blockIdx.x * 2) + (n >> 6);
            int nl = n & 63;
            int b = w2 >> 8, wi = w2 & 255;
            int wh = wi >> 4, wwi = wi & 15;
            int sr = wh * 8 + (nl >> 3), sc = wwi * 8 + (nl & 7);
            int h2 = (sr + 4) & 127, w2c = (sc + 4) & 127;
            tokb[rt][reg] = ((size_t)(b * 16384 + h2 * 128 + w2c)) * 192;
        }

    __syncthreads();

    ffrag acc[2][12];
    #pragma unroll
    for (int rt = 0; rt < 2; rt++)
        #pragma unroll
        for (int ct = 0; ct < 12; ct++)
            acc[rt][ct] = (ffrag){0.f, 0.f, 0.f, 0.f};

    #pragma unroll
    for (int ct = 0; ct < 12; ct++) {
        bfrag bw[6];
        #pragma unroll
        for (int kb = 0; kb < 6; kb++)
            bw[kb] = *(const bfrag*)&sWp[(ct * 16 + l15) * 200 + kb * 32 + quad * 8];
        #pragma unroll
        for (int rt = 0; rt < 2; rt++)
            #pragma unroll
            for (int kb = 0; kb < 6; kb++)
                acc[rt][ct] = MFMA(aO[rt][kb], bw[kb], acc[rt][ct]);
    }

    #pragma unroll
    for (int rt = 0; rt < 2; rt++)
        #pragma unroll
        for (int ct = 0; ct < 12; ct++) {
            int col = ct * 16 + l15;
            float pb = proj_b[col];
            #pragma unroll
            for (int reg = 0; reg < 4; reg++) {
                size_t gi = tokb[rt][reg] + col;
                xres[gi] = acc[rt][ct][reg] + pb + x[gi];
            }
        }
}

// ---------------------------------------------------------------------------
// k_mlp: 128 rows/block, 4 waves x 32 rows (rt=2). 12 chunks of 64 hidden,
// w1/w2 chunks staged per kc. LDS 71680 -> 2 blocks/CU. (R0 fused version)
// ---------------------------------------------------------------------------
__global__ __launch_bounds__(256, 2) void k_mlp(
    const float* __restrict__ xres, const float* __restrict__ g,
    const float* __restrict__ bb, const float* __restrict__ b1,
    const float* __restrict__ b2, const char* __restrict__ ws,
    float* __restrict__ out)
{
    __shared__ __align__(16) unsigned char smem[71680];
    bf16* U   = (bf16*)(smem);             // xn [128][200]; then w1 chunk [64][200]
    bf16* W2s = (bf16*)(smem + 25600);     // w2 chunk [192][72] (27648 B)
    bf16* hS  = (bf16*)(smem + 53248);     // [4][32][72]

    const bf16* w1T = (const bf16*)(ws + WS_W1T);
    const bf16* w2T = (const bf16*)(ws + WS_W2T);

    const int t    = threadIdx.x;
    const int lane = t & 63, quad = lane >> 4, l15 = lane & 15;
    const int wave = t >> 6, r0 = wave * 32;
    const size_t row0 = (size_t)blockIdx.x * 128;

    // ---- wave-local LayerNorm -> xn (bf16, U) ----
    #pragma unroll
    for (int p = 0; p < 2; p++) {
        int row = r0 + p * 16 + l15;
        const float4* src = (const float4*)(xres + (row0 + row) * 192 + quad * 48);
        float v[48];
        float s = 0.f, sq = 0.f;
        #pragma unroll
        for (int u = 0; u < 12; u++) {
            float4 f = src[u];
            v[u*4] = f.x; v[u*4+1] = f.y; v[u*4+2] = f.z; v[u*4+3] = f.w;
            s  += f.x + f.y + f.z + f.w;
            sq += f.x*f.x + f.y*f.y + f.z*f.z + f.w*f.w;
        }
        s  += __shfl_xor(s, 16);  s  += __shfl_xor(s, 32);
        sq += __shfl_xor(sq, 16); sq += __shfl_xor(sq, 32);
        float mean = s * (1.f / 192.f);
        float var  = sq * (1.f / 192.f) - mean * mean;
        float rstd = rsqrtf(var + 1e-5f);
        __hip_bfloat162* dst = (__hip_bfloat162*)&U[row * 200 + quad * 48];
        #pragma unroll
        for (int u = 0; u < 24; u++) {
            int c = quad * 48 + u * 2;
            float a0 = (v[u*2]   - mean) * rstd * g[c]     + bb[c];
            float a1 = (v[u*2+1] - mean) * rstd * g[c + 1] + bb[c + 1];
            dst[u] = __float22bfloat162_rn({a0, a1});
        }
    }

    // A-frags of xn (own rows; within-wave RAW)
    bfrag aX[2][6];
    #pragma unroll
    for (int rt = 0; rt < 2; rt++)
        #pragma unroll
        for (int kb = 0; kb < 6; kb++)
            aX[rt][kb] = *(const bfrag*)&U[(r0 + rt*16 + l15) * 200 + kb*32 + quad*8];

    __syncthreads();   // everyone done with xn region

    bf16* hs_w = hS + wave * 32 * 72;

    ffrag oacc[2][12];
    #pragma unroll
    for (int rt = 0; rt < 2; rt++)
        #pragma unroll
        for (int ct = 0; ct < 12; ct++)
            oacc[rt][ct] = (ffrag){0.f, 0.f, 0.f, 0.f};

    for (int kc = 0; kc < 12; kc++) {
        __syncthreads();                                   // WAR vs previous compute
        stage_lds(w1T + (size_t)kc * 64 * 200, U, 25600, t);
        stage_lds(w2T + (size_t)kc * 13824, W2s, 27648, t);
        __syncthreads();                                   // staging complete

        // MLP1 (64 hidden cols) + GELU -> hS (own rows)
        #pragma unroll
        for (int ct = 0; ct < 4; ct++) {
            bfrag bw[6];
            #pragma unroll
            for (int kb = 0; kb < 6; kb++)
                bw[kb] = *(const bfrag*)&U[(ct*16 + l15) * 200 + kb*32 + quad*8];
            float bias = b1[kc * 64 + ct * 16 + l15];
            #pragma unroll
            for (int rt = 0; rt < 2; rt++) {
                ffrag a = {0.f, 0.f, 0.f, 0.f};
                #pragma unroll
                for (int kb = 0; kb < 6; kb++) a = MFMA(aX[rt][kb], bw[kb], a);
                #pragma unroll
                for (int reg = 0; reg < 4; reg++)
                    hs_w[(rt*16 + quad*4 + reg) * 72 + ct*16 + l15] =
                        f2b(gelu_t(a[reg] + bias));
            }
        }
        // MLP2 over this 64-k chunk
        bfrag aH[2][2];
        #pragma unroll
        for (int rt = 0; rt < 2; rt++)
            #pragma unroll
            for (int k0 = 0; k0 < 2; k0++)
                aH[rt][k0] = *(const bfrag*)&hs_w[(rt*16 + l15) * 72 + k0*32 + quad*8];
        #pragma unroll
        for (int ct = 0; ct < 12; ct++) {
            bfrag bw2[2];
            #pragma unroll
            for (int k0 = 0; k0 < 2; k0++)
                bw2[k0] = *(const bfrag*)&W2s[(ct*16 + l15) * 72 + k0*32 + quad*8];
            #pragma unroll
            for (int rt = 0; rt < 2; rt++)
                #pragma unroll
                for (int k0 = 0; k0 < 2; k0++)
                    oacc[rt][ct] = MFMA(aH[rt][k0], bw2[k0], oacc[rt][ct]);
        }
    }

    // ---- epilogue: out = xres + mlp + b2 ----
    #pragma unroll
    for (int rt = 0; rt < 2; rt++)
        #pragma unroll
        for (int ct = 0; ct < 12; ct++) {
            int col = ct * 16 + l15;
            float b2v = b2[col];
            #pragma unroll
            for (int reg = 0; reg < 4; reg++) {
                size_t gi = (row0 + r0 + rt*16 + quad*4 + reg) * 192 + col;
                out[gi] = xres[gi] + oacc[rt][ct][reg] + b2v;
            }
        }
}

// ---------------------------------------------------------------------------
extern "C" void kernel_launch(void* const* d_in, const int* in_sizes, int n_in,
                              void* d_out, int out_size, void* d_ws, size_t ws_size,
                              hipStream_t stream)
{
    (void)in_sizes; (void)n_in; (void)out_size; (void)ws_size;

    const float* x      = (const float*)d_in[0];
    const float* qkv_w  = (const float*)d_in[1];
    const float* qkv_b  = (const float*)d_in[2];
    const float* proj_w = (const float*)d_in[3];
    const float* proj_b = (const float*)d_in[4];
    const float* rpb    = (const float*)d_in[5];
    const float* n2g    = (const float*)d_in[6];
    const float* n2b    = (const float*)d_in[7];
    const float* w1     = (const float*)d_in[8];
    const float* b1     = (const float*)d_in[9];
    const float* w2     = (const float*)d_in[10];
    const float* b2     = (const float*)d_in[11];

    char*  ws   = (char*)d_ws;
    float* xres = (float*)(ws + WS_XRES);
    bf16*  Og   = (bf16*)(ws + WS_OG);
    float* out  = (float*)d_out;

    hipLaunchKernelGGL(k_prep, dim3(2285), dim3(256), 0, stream,
                       qkv_w, qkv_b, proj_w, w1, w2, rpb, ws);
    hipLaunchKernelGGL(k_attn, dim3(2048), dim3(256), 0, stream,
                       x, ws, Og);
    hipLaunchKernelGGL(k_proj, dim3(1024), dim3(256), 0, stream,
                       x, proj_b, ws, xres);
    hipLaunchKernelGGL(k_mlp,  dim3(1024), dim3(256), 0, stream,
                       xres, n2g, n2b, b1, b2, ws, out);
}

// Round 6
// 470.527 us; speedup vs baseline: 1.2842x; 1.0179x over previous
//
#include <hip/hip_runtime.h>
#include <hip/hip_bf16.h>

// Swin block fp32 I/O, MFMA bf16 compute. B=8,H=W=128,C=192,NH=6,hd=32,WS=8,SS=4.
// Round 11: k_proj FUSED into k_attn. Per head h, PV output o is bounced
// through the wave's sP scratch (D-layout -> A-frag transpose, wave-local)
// and accumulated into acc[12] += O[:,32h:+32] @ projW[32h:+32,:] using
// per-head proj weight slabs [192][40] staged at cc=3h+1. Epilogue does the
// reverse-shift scatter RMW (xres = acc + proj_b + x). Og round-trip (100 MB)
// and the entire k_proj launch are eliminated. 3 kernels total.
// k_mlp = R0 fused version (plateau ~168us; do not re-schedule).
//
// MFMA 16x16x32 bf16 layouts (HW-verified):
//   A: a[j] = A[m=lane&15][k=quad*8+j]
//   B: b[j] = B[k=quad*8+j][n=lane&15]
//   D: d[reg] = D[row=quad*4+reg][col=lane&15]

typedef __hip_bfloat16 bf16;
typedef __attribute__((ext_vector_type(8))) short bfrag;
typedef __attribute__((ext_vector_type(4))) float ffrag;

union bfu { bf16 h[8]; bfrag v; };

__device__ __forceinline__ float b2f(bf16 v) { return __bfloat162float(v); }
__device__ __forceinline__ bf16  f2b(float v) { return __float2bfloat16(v); }

#define MFMA(a, b, c) __builtin_amdgcn_mfma_f32_16x16x32_bf16((a), (b), (c), 0, 0, 0)

// workspace byte offsets
#define WS_XRES  0ULL
#define WS_OG    100663296ULL                  // (unused this round)
#define WS_QKVTG 150994944ULL                  // bf16 [2][320][200] HEAD-MAJOR qkv_w^T
#define WS_QBG   151250944ULL                  // f32  [2][320] head-major qkv_b
#define WS_PROJT 151253504ULL                  // (legacy projT region, unused)
#define WS_W1T   151330304ULL                  // bf16 [768][200]
#define WS_W2T   151637504ULL                  // bf16 [12][192][72]
#define WS_SB    151969280ULL                  // bf16 [4][6][64][64]
#define WS_PROJH 152165888ULL                  // bf16 [6][192][40] per-head proj slabs

// async contiguous global->LDS copy; 256 threads; handles partial tails
__device__ __forceinline__ void stage_lds(const void* g, void* l, int nbytes, int t) {
    const int lane16 = (t & 63) * 16;
    for (int base = (t >> 6) * 1024; base < nbytes; base += 4096) {
        if (base + lane16 < nbytes) {
            __builtin_amdgcn_global_load_lds(
                (const __attribute__((address_space(1))) void*)((const char*)g + base + lane16),
                (__attribute__((address_space(3))) void*)((char*)l + base),
                16, 0, 0);
        }
    }
}

__device__ __forceinline__ float gelu_t(float x) {
    float y = x * (1.5957691216057308f + 0.07135481627f * x * x);
    return x * (1.f / (1.f + __expf(-y)));
}

// ---------------------------------------------------------------------------
// k_prep: 2465 x 256 covers 630912 elements
// ---------------------------------------------------------------------------
__global__ __launch_bounds__(256) void k_prep(
    const float* __restrict__ qkv_w, const float* __restrict__ qkv_b,
    const float* __restrict__ proj_w, const float* __restrict__ w1,
    const float* __restrict__ w2, const float* __restrict__ rpb,
    char* __restrict__ ws)
{
    int i = blockIdx.x * 256 + threadIdx.x;
    bf16*  qkvTg = (bf16*)(ws + WS_QKVTG);
    float* qbg   = (float*)(ws + WS_QBG);
    bf16*  projT = (bf16*)(ws + WS_PROJT);
    bf16*  w1T   = (bf16*)(ws + WS_W1T);
    bf16*  w2T   = (bf16*)(ws + WS_W2T);
    bf16*  sbB   = (bf16*)(ws + WS_SB);
    bf16*  projH = (bf16*)(ws + WS_PROJH);

    if (i < 128000) {                          // qkvTg [2][320][200] head-major
        int g = i / 64000, rem = i % 64000;
        int c = rem / 200, k = rem % 200;
        float v = 0.f;
        if (k < 192 && c < 288) {
            int h = g * 3 + c / 96, j = c % 96;
            int src = (j < 32) ? (h * 32 + j)
                    : (j < 64) ? (192 + h * 32 + (j - 32))
                               : (384 + h * 32 + (j - 64));
            v = qkv_w[k * 576 + src];
        }
        qkvTg[i] = f2b(v);
    } else if (i < 128640) {                   // qbg [2][320] head-major
        int j = i - 128000;
        int g = j / 320, c = j % 320;
        float v = 0.f;
        if (c < 288) {
            int h = g * 3 + c / 96, jj = c % 96;
            int src = (jj < 32) ? (h * 32 + jj)
                    : (jj < 64) ? (192 + h * 32 + (jj - 32))
                                : (384 + h * 32 + (jj - 64));
            v = qkv_b[src];
        }
        qbg[j] = v;
    } else if (i < 167040) {                   // legacy projT [192][200] (unused)
        int j = i - 128640;
        int c = j / 200, k = j % 200;
        projT[j] = f2b(k < 192 ? proj_w[k * 192 + c] : 0.f);
    } else if (i < 320640) {                   // w1T [768][200]
        int j = i - 167040;
        int c = j / 200, k = j % 200;
        w1T[j] = f2b(k < 192 ? w1[k * 768 + c] : 0.f);
    } else if (i < 486528) {                   // w2T [12][192][72]
        int j = i - 320640;
        int kc = j / 13824, r = (j % 13824) / 72, kk = j % 72;
        w2T[j] = f2b(kk < 64 ? w2[(kc * 64 + kk) * 192 + r] : 0.f);
    } else if (i < 584832) {                   // sbB [4][6][64][64]
        int j = i - 486528;
        int cls = j / 24576, h = (j % 24576) / 4096;
        int ii = (j % 4096) / 64, jj = j % 64;
        int ri = ii >> 3, ci = ii & 7, rj = jj >> 3, cj = jj & 7;
        float bias = rpb[(((ri - rj + 7) * 15) + (ci - cj + 7)) * 6 + h];
        int clsR = cls >> 1, clsC = cls & 1;
        int regi = (clsR ? (ri < 4 ? 1 : 2) : 0) * 3 + (clsC ? (ci < 4 ? 1 : 2) : 0);
        int regj = (clsR ? (rj < 4 ? 1 : 2) : 0) * 3 + (clsC ? (cj < 4 ? 1 : 2) : 0);
        sbB[j] = f2b(bias + (regi == regj ? 0.f : -100.f));
    } else if (i < 630912) {                   // projH [6][192][40]
        int j = i - 584832;
        int s = j / 7680, c = (j % 7680) / 40, kk = j % 40;
        projH[j] = f2b(kk < 32 ? proj_w[(s * 32 + kk) * 192 + c] : 0.f);
    }
}

// ---------------------------------------------------------------------------
// k_attn (+fused proj): one window/block, 4 waves x 16 rows, HEAD-MAJOR.
// 18 qkv chunks of 32 cols (double-buffered); per head: attention, then o is
// bounced via sP (wave-local) and accumulated into acc[12] with the head's
// proj slab (staged at cc=3h+1, single-buffered). Epilogue: reverse-shift
// scatter RMW. LDS 67584 -> 2 blocks/CU.
// ---------------------------------------------------------------------------
__global__ __launch_bounds__(256, 2) void k_attn(
    const float* __restrict__ x, const char* __restrict__ ws,
    const float* __restrict__ proj_b, float* __restrict__ xres)
{
    __shared__ __align__(16) unsigned char smem[67584];
    bf16*  sWb   = (bf16*)(smem);            // 2 x [32][200] double-buffered chunk
    bf16*  sQh   = (bf16*)(smem + 25600);    // [64][40] head Q
    bf16*  sKh   = (bf16*)(smem + 30720);    // [64][40] head K
    bf16*  sVT   = (bf16*)(smem + 35840);    // [32][72] head V^T
    bf16*  sP    = (bf16*)(smem + 40448);    // [4][16][72] P / o-bounce scratch
    float* sQB   = (float*)(smem + 49664);   // [640] qkv bias (head-major)
    bf16*  sProj = (bf16*)(smem + 52224);    // [192][40] proj slab (head h)

    const bf16*  qkvTg = (const bf16*)(ws + WS_QKVTG);
    const float* qbg   = (const float*)(ws + WS_QBG);
    const bf16*  sbB   = (const bf16*)(ws + WS_SB);
    const bf16*  projH = (const bf16*)(ws + WS_PROJH);

    const int t    = threadIdx.x;
    const int lane = t & 63, quad = lane >> 4, l15 = lane & 15;
    const int wave = t >> 6, r0 = wave * 16;
    const int win = blockIdx.x;
    const int b   = win >> 8;
    const int wi  = win & 255;
    const int wh  = wi >> 4, wwi = wi & 15;

    // prologue staging: biases + qkv chunk 0 + proj slab 0
    stage_lds(qbg, smem + 49664, 2560, t);
    stage_lds(qkvTg, sWb, 12800, t);
    stage_lds(projH, sProj, 15360, t);

    // A-frags of gathered x window, direct from global (fp32 -> bf16)
    bfrag aX[6];
    {
        int row = r0 + l15;
        int rr = row >> 3, cc = row & 7;
        int hs  = (wh * 8 + rr + 4) & 127;
        int wsx = (wwi * 8 + cc + 4) & 127;
        const float* xrow = x + ((size_t)(b * 16384 + hs * 128 + wsx)) * 192;
        #pragma unroll
        for (int kb = 0; kb < 6; kb++) {
            float4 f0 = *(const float4*)(xrow + kb * 32 + quad * 8);
            float4 f1 = *(const float4*)(xrow + kb * 32 + quad * 8 + 4);
            bfu u;
            u.h[0] = f2b(f0.x); u.h[1] = f2b(f0.y); u.h[2] = f2b(f0.z); u.h[3] = f2b(f0.w);
            u.h[4] = f2b(f1.x); u.h[5] = f2b(f1.y); u.h[6] = f2b(f1.z); u.h[7] = f2b(f1.w);
            aX[kb] = u.v;
        }
    }

    // reverse-shift scatter bases for this wave's 4 output rows (quad*4+reg)
    size_t tokb[4];
    #pragma unroll
    for (int reg = 0; reg < 4; reg++) {
        int nl = r0 + quad * 4 + reg;
        int sr = wh * 8 + (nl >> 3), sc = wwi * 8 + (nl & 7);
        int h2 = (sr + 4) & 127, w2c = (sc + 4) & 127;
        tokb[reg] = ((size_t)(b * 16384 + h2 * 128 + w2c)) * 192;
    }

    const int cls = ((wh == 15) ? 2 : 0) + ((wwi == 15) ? 1 : 0);
    const bf16* bBc = sbB + (size_t)cls * 24576;
    bf16* sPw = sP + wave * 16 * 72;

    ffrag acc[12];
    #pragma unroll
    for (int ct = 0; ct < 12; ct++)
        acc[ct] = (ffrag){0.f, 0.f, 0.f, 0.f};

    __syncthreads();                           // chunk0 + slab0 + biases staged

    int pb = 0;
    int cb = 0;                                // col base in [2][320] image
    for (int cc = 0; cc < 18; cc++) {
        const int h = cc / 3, cpart = cc - h * 3;
        // stage next qkv chunk (col base: +32, or jump 256->320 at group switch)
        if (cc < 17) {
            int cbn = (cc == 8) ? 320 : cb + 32;
            stage_lds(qkvTg + (size_t)cbn * 200, sWb + (pb ^ 1) * 6400, 12800, t);
        }
        // stage proj slab for head cc/3 at cc=3h+1 (slab h-1 last read two
        // barriers ago in cc=3h-1 -> WAR-safe)
        if (cpart == 1 && cc >= 4)
            stage_lds(projH + (size_t)h * 7680, sProj, 15360, t);

        const bf16* sW = sWb + pb * 6400;
        #pragma unroll
        for (int ct = 0; ct < 2; ct++) {
            bfrag bw[6];
            #pragma unroll
            for (int kb = 0; kb < 6; kb++)
                bw[kb] = *(const bfrag*)&sW[(ct * 16 + l15) * 200 + kb * 32 + quad * 8];
            ffrag qacc = {0.f, 0.f, 0.f, 0.f};
            #pragma unroll
            for (int kb = 0; kb < 6; kb++) qacc = MFMA(aX[kb], bw[kb], qacc);
            float bias = sQB[cb + ct * 16 + l15];
            const int cl = ct * 16 + l15;
            #pragma unroll
            for (int reg = 0; reg < 4; reg++) {
                int r = r0 + quad * 4 + reg;
                float v = qacc[reg] + bias;
                if (cpart == 0)      sQh[r * 40 + cl] = f2b(v);
                else if (cpart == 1) sKh[r * 40 + cl] = f2b(v);
                else                 sVT[cl * 72 + r] = f2b(v);
            }
        }
        __syncthreads();                       // drains prefetch; scatters visible
        pb ^= 1;
        cb = (cc == 8) ? 320 : cb + 32;

        if (cpart == 2) {
            // ---- attention head h (sQh/sKh/sVT complete) ----
            bfrag aQ = *(const bfrag*)&sQh[(r0 + l15) * 40 + quad * 8];
            ffrag Sf[4];
            #pragma unroll
            for (int jt = 0; jt < 4; jt++) {
                bfrag bK = *(const bfrag*)&sKh[(jt * 16 + l15) * 40 + quad * 8];
                ffrag z = {0.f, 0.f, 0.f, 0.f};
                Sf[jt] = MFMA(aQ, bK, z);
            }
            const bf16* bb = bBc + h * 4096 + (r0 + quad * 4) * 64 + l15;
            #pragma unroll
            for (int jt = 0; jt < 4; jt++)
                #pragma unroll
                for (int reg = 0; reg < 4; reg++)
                    Sf[jt][reg] = Sf[jt][reg] * 0.1767766952966369f
                                + b2f(bb[reg * 64 + jt * 16]);
            #pragma unroll
            for (int reg = 0; reg < 4; reg++) {
                float m = fmaxf(fmaxf(Sf[0][reg], Sf[1][reg]), fmaxf(Sf[2][reg], Sf[3][reg]));
                m = fmaxf(m, __shfl_xor(m, 1)); m = fmaxf(m, __shfl_xor(m, 2));
                m = fmaxf(m, __shfl_xor(m, 4)); m = fmaxf(m, __shfl_xor(m, 8));
                float s = 0.f;
                #pragma unroll
                for (int jt = 0; jt < 4; jt++) { Sf[jt][reg] = __expf(Sf[jt][reg] - m); s += Sf[jt][reg]; }
                s += __shfl_xor(s, 1); s += __shfl_xor(s, 2);
                s += __shfl_xor(s, 4); s += __shfl_xor(s, 8);
                float inv = 1.f / s;
                int prow = (quad * 4 + reg) * 72;
                #pragma unroll
                for (int jt = 0; jt < 4; jt++)
                    sPw[prow + jt * 16 + l15] = f2b(Sf[jt][reg] * inv);
            }
            bfrag aP0 = *(const bfrag*)&sPw[l15 * 72 + quad * 8];
            bfrag aP1 = *(const bfrag*)&sPw[l15 * 72 + 32 + quad * 8];
            ffrag o[2];
            #pragma unroll
            for (int ct = 0; ct < 2; ct++) {
                bfrag bV0 = *(const bfrag*)&sVT[(ct * 16 + l15) * 72 + quad * 8];
                bfrag bV1 = *(const bfrag*)&sVT[(ct * 16 + l15) * 72 + 32 + quad * 8];
                ffrag z = {0.f, 0.f, 0.f, 0.f};
                o[ct] = MFMA(aP1, bV1, MFMA(aP0, bV0, z));
            }
            // ---- fused proj: bounce o (D-layout) -> A-frag via sPw, then
            //      acc[ct2] += O[:,32h:+32] @ projW[32h:+32, ct2*16:+16]
            #pragma unroll
            for (int ct = 0; ct < 2; ct++)
                #pragma unroll
                for (int reg = 0; reg < 4; reg++)
                    sPw[(quad * 4 + reg) * 40 + ct * 16 + l15] = f2b(o[ct][reg]);
            bfrag aO = *(const bfrag*)&sPw[l15 * 40 + quad * 8];
            #pragma unroll
            for (int ct2 = 0; ct2 < 12; ct2++) {
                bfrag bwp = *(const bfrag*)&sProj[(ct2 * 16 + l15) * 40 + quad * 8];
                acc[ct2] = MFMA(aO, bwp, acc[ct2]);
            }
            if (cc < 17) __syncthreads();      // attn/proj reads done before next head
        }
    }

    // ---- epilogue: xres = O @ projW + proj_b + x (reverse-shift scatter) ----
    #pragma unroll
    for (int ct2 = 0; ct2 < 12; ct2++) {
        int col = ct2 * 16 + l15;
        float pbv = proj_b[col];
        #pragma unroll
        for (int reg = 0; reg < 4; reg++) {
            size_t gi = tokb[reg] + col;
            xres[gi] = acc[ct2][reg] + pbv + x[gi];
        }
    }
}

// ---------------------------------------------------------------------------
// k_mlp: 128 rows/block, 4 waves x 32 rows (rt=2). 12 chunks of 64 hidden,
// w1/w2 chunks staged per kc. LDS 71680 -> 2 blocks/CU. (R0 fused version)
// ---------------------------------------------------------------------------
__global__ __launch_bounds__(256, 2) void k_mlp(
    const float* __restrict__ xres, const float* __restrict__ g,
    const float* __restrict__ bb, const float* __restrict__ b1,
    const float* __restrict__ b2, const char* __restrict__ ws,
    float* __restrict__ out)
{
    __shared__ __align__(16) unsigned char smem[71680];
    bf16* U   = (bf16*)(smem);             // xn [128][200]; then w1 chunk [64][200]
    bf16* W2s = (bf16*)(smem + 25600);     // w2 chunk [192][72] (27648 B)
    bf16* hS  = (bf16*)(smem + 53248);     // [4][32][72]

    const bf16* w1T = (const bf16*)(ws + WS_W1T);
    const bf16* w2T = (const bf16*)(ws + WS_W2T);

    const int t    = threadIdx.x;
    const int lane = t & 63, quad = lane >> 4, l15 = lane & 15;
    const int wave = t >> 6, r0 = wave * 32;
    const size_t row0 = (size_t)blockIdx.x * 128;

    // ---- wave-local LayerNorm -> xn (bf16, U) ----
    #pragma unroll
    for (int p = 0; p < 2; p++) {
        int row = r0 + p * 16 + l15;
        const float4* src = (const float4*)(xres + (row0 + row) * 192 + quad * 48);
        float v[48];
        float s = 0.f, sq = 0.f;
        #pragma unroll
        for (int u = 0; u < 12; u++) {
            float4 f = src[u];
            v[u*4] = f.x; v[u*4+1] = f.y; v[u*4+2] = f.z; v[u*4+3] = f.w;
            s  += f.x + f.y + f.z + f.w;
            sq += f.x*f.x + f.y*f.y + f.z*f.z + f.w*f.w;
        }
        s  += __shfl_xor(s, 16);  s  += __shfl_xor(s, 32);
        sq += __shfl_xor(sq, 16); sq += __shfl_xor(sq, 32);
        float mean = s * (1.f / 192.f);
        float var  = sq * (1.f / 192.f) - mean * mean;
        float rstd = rsqrtf(var + 1e-5f);
        __hip_bfloat162* dst = (__hip_bfloat162*)&U[row * 200 + quad * 48];
        #pragma unroll
        for (int u = 0; u < 24; u++) {
            int c = quad * 48 + u * 2;
            float a0 = (v[u*2]   - mean) * rstd * g[c]     + bb[c];
            float a1 = (v[u*2+1] - mean) * rstd * g[c + 1] + bb[c + 1];
            dst[u] = __float22bfloat162_rn({a0, a1});
        }
    }

    // A-frags of xn (own rows; within-wave RAW)
    bfrag aX[2][6];
    #pragma unroll
    for (int rt = 0; rt < 2; rt++)
        #pragma unroll
        for (int kb = 0; kb < 6; kb++)
            aX[rt][kb] = *(const bfrag*)&U[(r0 + rt*16 + l15) * 200 + kb*32 + quad*8];

    __syncthreads();   // everyone done with xn region

    bf16* hs_w = hS + wave * 32 * 72;

    ffrag oacc[2][12];
    #pragma unroll
    for (int rt = 0; rt < 2; rt++)
        #pragma unroll
        for (int ct = 0; ct < 12; ct++)
            oacc[rt][ct] = (ffrag){0.f, 0.f, 0.f, 0.f};

    for (int kc = 0; kc < 12; kc++) {
        __syncthreads();                                   // WAR vs previous compute
        stage_lds(w1T + (size_t)kc * 64 * 200, U, 25600, t);
        stage_lds(w2T + (size_t)kc * 13824, W2s, 27648, t);
        __syncthreads();                                   // staging complete

        // MLP1 (64 hidden cols) + GELU -> hS (own rows)
        #pragma unroll
        for (int ct = 0; ct < 4; ct++) {
            bfrag bw[6];
            #pragma unroll
            for (int kb = 0; kb < 6; kb++)
                bw[kb] = *(const bfrag*)&U[(ct*16 + l15) * 200 + kb*32 + quad*8];
            float bias = b1[kc * 64 + ct * 16 + l15];
            #pragma unroll
            for (int rt = 0; rt < 2; rt++) {
                ffrag a = {0.f, 0.f, 0.f, 0.f};
                #pragma unroll
                for (int kb = 0; kb < 6; kb++) a = MFMA(aX[rt][kb], bw[kb], a);
                #pragma unroll
                for (int reg = 0; reg < 4; reg++)
                    hs_w[(rt*16 + quad*4 + reg) * 72 + ct*16 + l15] =
                        f2b(gelu_t(a[reg] + bias));
            }
        }
        // MLP2 over this 64-k chunk
        bfrag aH[2][2];
        #pragma unroll
        for (int rt = 0; rt < 2; rt++)
            #pragma unroll
            for (int k0 = 0; k0 < 2; k0++)
                aH[rt][k0] = *(const bfrag*)&hs_w[(rt*16 + l15) * 72 + k0*32 + quad*8];
        #pragma unroll
        for (int ct = 0; ct < 12; ct++) {
            bfrag bw2[2];
            #pragma unroll
            for (int k0 = 0; k0 < 2; k0++)
                bw2[k0] = *(const bfrag*)&W2s[(ct*16 + l15) * 72 + k0*32 + quad*8];
            #pragma unroll
            for (int rt = 0; rt < 2; rt++)
                #pragma unroll
                for (int k0 = 0; k0 < 2; k0++)
                    oacc[rt][ct] = MFMA(aH[rt][k0], bw2[k0], oacc[rt][ct]);
        }
    }

    // ---- epilogue: out = xres + mlp + b2 ----
    #pragma unroll
    for (int rt = 0; rt < 2; rt++)
        #pragma unroll
        for (int ct = 0; ct < 12; ct++) {
            int col = ct * 16 + l15;
            float b2v = b2[col];
            #pragma unroll
            for (int reg = 0; reg < 4; reg++) {
                size_t gi = (row0 + r0 + rt*16 + quad*4 + reg) * 192 + col;
                out[gi] = xres[gi] + oacc[rt][ct][reg] + b2v;
            }
        }
}

// ---------------------------------------------------------------------------
extern "C" void kernel_launch(void* const* d_in, const int* in_sizes, int n_in,
                              void* d_out, int out_size, void* d_ws, size_t ws_size,
                              hipStream_t stream)
{
    (void)in_sizes; (void)n_in; (void)out_size; (void)ws_size;

    const float* x      = (const float*)d_in[0];
    const float* qkv_w  = (const float*)d_in[1];
    const float* qkv_b  = (const float*)d_in[2];
    const float* proj_w = (const float*)d_in[3];
    const float* proj_b = (const float*)d_in[4];
    const float* rpb    = (const float*)d_in[5];
    const float* n2g    = (const float*)d_in[6];
    const float* n2b    = (const float*)d_in[7];
    const float* w1     = (const float*)d_in[8];
    const float* b1     = (const float*)d_in[9];
    const float* w2     = (const float*)d_in[10];
    const float* b2     = (const float*)d_in[11];

    char*  ws   = (char*)d_ws;
    float* xres = (float*)(ws + WS_XRES);
    float* out  = (float*)d_out;

    hipLaunchKernelGGL(k_prep, dim3(2465), dim3(256), 0, stream,
                       qkv_w, qkv_b, proj_w, w1, w2, rpb, ws);
    hipLaunchKernelGGL(k_attn, dim3(2048), dim3(256), 0, stream,
                       x, ws, proj_b, xres);
    hipLaunchKernelGGL(k_mlp,  dim3(1024), dim3(256), 0, stream,
                       xres, n2g, n2b, b1, b2, ws, out);
}